// Round 1
// baseline (926.898 us; speedup 1.0000x reference)
//
#include <hip/hip_runtime.h>
#include <cstdint>

// Problem constants (from reference setup_inputs)
constexpr int Bv = 16, Nv = 4096, Fv = 512, Sv = 8, Kv = 1024, Dv = 64;
constexpr int Mv = Bv * Nv;            // 65536 rows
constexpr int TM = 64;                 // rows per block tile
constexpr int TK = 128;                // codewords per K-tile
constexpr int NKT = Kv / TK;           // 8 K-tiles
#define BDIM 256

__device__ __forceinline__ void gload_lds16(const float* g, float* lds) {
  __builtin_amdgcn_global_load_lds(
      (const __attribute__((address_space(1))) void*)g,
      (__attribute__((address_space(3))) void*)lds, 16, 0, 0);
}

// c2h[s*K + k] = 0.5 * sum_d codebooks[s][k][d]^2
__global__ void c2half_kernel(const float* __restrict__ cb, float* __restrict__ c2h) {
  int idx = blockIdx.x * blockDim.x + threadIdx.x;  // 0..S*K-1
  const float4* p = (const float4*)(cb + (size_t)idx * Dv);
  float s = 0.f;
#pragma unroll
  for (int i = 0; i < 16; ++i) {
    float4 v = p[i];
    s += v.x * v.x + v.y * v.y + v.z * v.z + v.w * v.w;
  }
  c2h[idx] = 0.5f * s;
}

// Main kernel: one block = 64 rows x 1 subspace. Score = 0.5*c2 - <xs, c_k>,
// argmin over k, write selected codeword to quant, accumulate dev partials.
__global__ __launch_bounds__(BDIM, 2) void pq_main(
    const float* __restrict__ x, const float* __restrict__ cb,
    const float* __restrict__ c2h, float* __restrict__ quant,
    float* __restrict__ devpart) {
  __shared__ __attribute__((aligned(16))) float cb_lds[TK * Dv];  // 32KB, swizzled
  __shared__ __attribute__((aligned(16))) float xs_lds[TM * Dv];  // 16KB, swizzled
  __shared__ float red_v[TM][16];
  __shared__ int red_i[TM][16];
  __shared__ int bidx_sh[TM];
  __shared__ float sred[BDIM];

  const int tid = threadIdx.x;
  const int s = blockIdx.y;
  const int row0 = blockIdx.x * TM;
  const int rg = tid & 15;   // row group: rows rg*4 .. rg*4+3
  const int cg = tid >> 4;   // cb group: cbs cg*8 .. cg*8+7

  // ---- stage xs tile (64 rows x 64 floats), LDS linear dest + swizzled global src.
  // LDS f4-slot p4 = (r, d4p) holds global f4 d4 = d4p ^ ((r>>2)&7)
#pragma unroll
  for (int it = 0; it < 4; ++it) {
    int p4 = it * BDIM + tid;
    int r = p4 >> 4;
    int gd4 = (p4 & 15) ^ ((r >> 2) & 7);
    const float* src = x + (size_t)(row0 + r) * Fv + s * Dv + gd4 * 4;
    float* dst = xs_lds + (size_t)(it * BDIM + (tid & ~63)) * 4;  // wave-uniform base
    gload_lds16(src, dst);
  }

  float bestv[4];
  int besti[4];
#pragma unroll
  for (int i = 0; i < 4; ++i) { bestv[i] = 3.0e38f; besti[i] = 0; }

  const int key4x = rg & 7;  // == (r>>2)&7 for r = rg*4+i, i<4
  const int key4c = cg & 7;  // == (row>>3)&7 for row = cg*8+j, j<8

  for (int kt = 0; kt < NKT; ++kt) {
    __syncthreads();  // previous tile's LDS reads done before overwrite
    // ---- stage cb tile (128 cbs x 64 floats); slot (r, d4p) holds d4 = d4p ^ ((r>>3)&7)
#pragma unroll
    for (int it = 0; it < 8; ++it) {
      int p4 = it * BDIM + tid;
      int r = p4 >> 4;
      int gd4 = (p4 & 15) ^ ((r >> 3) & 7);
      const float* src = cb + ((size_t)(s * Kv + kt * TK + r)) * Dv + gd4 * 4;
      float* dst = cb_lds + (size_t)(it * BDIM + (tid & ~63)) * 4;
      gload_lds16(src, dst);
    }
    float c2v[8];
#pragma unroll
    for (int j = 0; j < 8; ++j) c2v[j] = c2h[s * Kv + kt * TK + cg * 8 + j];
    __syncthreads();  // includes vmcnt(0) drain for global_load_lds

    float acc[4][8];
#pragma unroll
    for (int i = 0; i < 4; ++i)
#pragma unroll
      for (int j = 0; j < 8; ++j) acc[i][j] = c2v[j];

#pragma unroll
    for (int d4 = 0; d4 < 16; ++d4) {
      const int offx = 4 * (d4 ^ key4x);
      const int offc = 4 * (d4 ^ key4c);
      float4 xv[4], cv[8];
#pragma unroll
      for (int i = 0; i < 4; ++i)
        xv[i] = *(const float4*)&xs_lds[(rg * 4 + i) * Dv + offx];
#pragma unroll
      for (int j = 0; j < 8; ++j)
        cv[j] = *(const float4*)&cb_lds[(cg * 8 + j) * Dv + offc];
#pragma unroll
      for (int i = 0; i < 4; ++i)
#pragma unroll
        for (int j = 0; j < 8; ++j) {
          acc[i][j] = fmaf(-xv[i].x, cv[j].x, acc[i][j]);
          acc[i][j] = fmaf(-xv[i].y, cv[j].y, acc[i][j]);
          acc[i][j] = fmaf(-xv[i].z, cv[j].z, acc[i][j]);
          acc[i][j] = fmaf(-xv[i].w, cv[j].w, acc[i][j]);
        }
    }

    // fold into running argmin; per-thread k strictly ascending across (kt, j)
#pragma unroll
    for (int i = 0; i < 4; ++i)
#pragma unroll
      for (int j = 0; j < 8; ++j) {
        int k = kt * TK + cg * 8 + j;
        if (acc[i][j] < bestv[i]) { bestv[i] = acc[i][j]; besti[i] = k; }
      }
  }

  // ---- cross-thread argmin reduce (16 cb-groups per row)
#pragma unroll
  for (int i = 0; i < 4; ++i) {
    red_v[rg * 4 + i][cg] = bestv[i];
    red_i[rg * 4 + i][cg] = besti[i];
  }
  __syncthreads();
  if (tid < TM) {
    float bv = red_v[tid][0];
    int bi = red_i[tid][0];
#pragma unroll
    for (int c = 1; c < 16; ++c) {
      float v = red_v[tid][c];
      int ii = red_i[tid][c];
      if (v < bv || (v == bv && ii < bi)) { bv = v; bi = ii; }
    }
    bidx_sh[tid] = bi;
  }
  __syncthreads();

  // ---- epilogue: 4 threads per row, 16 floats each
  const int r = tid >> 2, q = tid & 3;
  const int kstar = bidx_sh[r];
  const float* sym = cb + ((size_t)(s * Kv + kstar)) * Dv;
  float* qout = quant + (size_t)(row0 + r) * Fv + s * Dv;
  float devacc = 0.f;
#pragma unroll
  for (int t = 0; t < 4; ++t) {
    int d4 = q + 4 * t;
    float4 sv = *(const float4*)&sym[d4 * 4];
    float4 xv = *(const float4*)&xs_lds[r * Dv + 4 * (d4 ^ ((r >> 2) & 7))];
    float dx = sv.x - xv.x, dy = sv.y - xv.y, dz = sv.z - xv.z, dw = sv.w - xv.w;
    devacc += dx * dx + dy * dy + dz * dz + dw * dw;
    *(float4*)&qout[d4 * 4] = sv;
  }
  sred[tid] = devacc;
  __syncthreads();
  for (int off = 128; off > 0; off >>= 1) {
    if (tid < off) sred[tid] += sred[tid + off];
    __syncthreads();
  }
  if (tid == 0) devpart[blockIdx.y * gridDim.x + blockIdx.x] = sred[0];
}

// Deterministic final reduction of 8192 block partials -> dev scalar
__global__ void dev_reduce(const float* __restrict__ part, float* __restrict__ out) {
  __shared__ float sred[256];
  int tid = threadIdx.x;
  float s = 0.f;
  for (int i = tid; i < (Mv / TM) * Sv; i += 256) s += part[i];
  sred[tid] = s;
  __syncthreads();
  for (int off = 128; off > 0; off >>= 1) {
    if (tid < off) sred[tid] += sred[tid + off];
    __syncthreads();
  }
  if (tid == 0) out[0] = sred[0] * (1.25f / (float)((size_t)Bv * Nv * Dv));
}

extern "C" void kernel_launch(void* const* d_in, const int* in_sizes, int n_in,
                              void* d_out, int out_size, void* d_ws, size_t ws_size,
                              hipStream_t stream) {
  const float* x = (const float*)d_in[0];        // (B, N, F) fp32
  const float* cb = (const float*)d_in[1];       // (S, K, D) fp32
  float* quant = (float*)d_out;                  // (B, N, F) fp32
  float* dev = quant + (size_t)Mv * Fv;          // scalar

  // workspace layout: [0 .. S*K) c2/2, [S*K .. S*K + 8192) block partials (64KB total)
  float* c2h = (float*)d_ws;
  float* part = c2h + Sv * Kv;

  c2half_kernel<<<(Sv * Kv) / 256, 256, 0, stream>>>(cb, c2h);
  dim3 grid(Mv / TM, Sv);
  pq_main<<<grid, BDIM, 0, stream>>>(x, cb, c2h, quant, part);
  dev_reduce<<<1, 256, 0, stream>>>(part, dev);
}

// Round 2
// 173.764 us; speedup vs baseline: 5.3342x; 5.3342x over previous
//
#include <hip/hip_runtime.h>
#include <cstdint>
#include <cstring>

constexpr int Bv = 16, Nv = 4096, Fv = 512, Sv = 8, Kv = 1024, Dv = 64;
constexpr int Mv = Bv * Nv;  // 65536 rows
#define BDIM 256

using bf16x8 = __attribute__((ext_vector_type(8))) short;
using f32x4  = __attribute__((ext_vector_type(4))) float;
typedef unsigned short u16;
typedef unsigned int u32;

__device__ __forceinline__ u16 bf16rne(float f) {
  union { float f; u32 u; } v; v.f = f;
  u32 u = v.u + 0x7FFFu + ((v.u >> 16) & 1u);
  return (u16)(u >> 16);
}

__device__ __forceinline__ void gload_lds16(const void* g, void* lds) {
  __builtin_amdgcn_global_load_lds(
      (const __attribute__((address_space(1))) void*)g,
      (__attribute__((address_space(3))) void*)lds, 16, 0, 0);
}

// prep: cb fp32 -> (a) swizzled bf16 codebook in ws, (b) c2h = 0.5*sum(c^2)
// swz layout: [s*1024+cw][slot'][8 bf16], where slot' = slot ^ (cw&7)
__global__ void prep_kernel(const float* __restrict__ cb, u16* __restrict__ swz,
                            float* __restrict__ c2h) {
  int idx = blockIdx.x * BDIM + threadIdx.x;  // 0..8191 = s*1024+cw
  int cw = idx & (Kv - 1);
  const float4* src = (const float4*)(cb + (size_t)idx * Dv);
  float v[64];
  float s2 = 0.f;
#pragma unroll
  for (int i = 0; i < 16; ++i) {
    float4 f = src[i];
    v[i * 4 + 0] = f.x; v[i * 4 + 1] = f.y; v[i * 4 + 2] = f.z; v[i * 4 + 3] = f.w;
    s2 += f.x * f.x + f.y * f.y + f.z * f.z + f.w * f.w;
  }
  c2h[idx] = 0.5f * s2;
  uint4* out = (uint4*)(swz + (size_t)idx * Dv);
#pragma unroll
  for (int slot = 0; slot < 8; ++slot) {
    int slotp = slot ^ (cw & 7);
    u32 w[4];
#pragma unroll
    for (int p = 0; p < 4; ++p)
      w[p] = (u32)bf16rne(v[slot * 8 + p * 2]) | ((u32)bf16rne(v[slot * 8 + p * 2 + 1]) << 16);
    uint4 pk; pk.x = w[0]; pk.y = w[1]; pk.z = w[2]; pk.w = w[3];
    out[slotp] = pk;
  }
}

// main: block = 256 rows x 1 subspace; wave = 64 rows x all 1024 codewords.
// score = 0.5*c2 - <x,c> via mfma(A=cb_bf16, B=-x_bf16, C=c2h); lane-local argmin.
__global__ __launch_bounds__(BDIM, 4) void pq_mfma(
    const float* __restrict__ x, const float* __restrict__ cb,
    const u16* __restrict__ swz, const float* __restrict__ c2h_g,
    float* __restrict__ quant, float* __restrict__ devpart) {
  __shared__ __attribute__((aligned(16))) u16 cb_lds[2][128 * Dv];  // 2 x 16KB
  __shared__ __attribute__((aligned(16))) float c2_lds[Kv];         // 4KB

  const int tid = threadIdx.x;
  const int s = blockIdx.y;
  const int row0 = blockIdx.x * 256;
  const int wave = tid >> 6, lane = tid & 63;
  const int l15 = lane & 15, lg = lane >> 4;
  const int slotp0 = lg ^ (lane & 7);       // h=0
  const int slotp1 = (4 + lg) ^ (lane & 7); // h=1

  // ---- stage c2 (4KB) + chunk 0 (16KB) via global_load_lds (linear dest)
  {
    const float* src = c2h_g + s * Kv + tid * 4;
    gload_lds16(src, &c2_lds[(tid & ~63) * 4]);
  }
  const u16* swz_s = swz + (size_t)s * Kv * Dv;
#pragma unroll
  for (int it = 0; it < 4; ++it) {
    gload_lds16(swz_s + (size_t)(it * BDIM + tid) * 8,
                &cb_lds[0][(it * BDIM + (tid & ~63)) * 8]);
  }

  // ---- load x rows into bf16 fragments (negated), accumulate fp32 x2 partials
  bf16x8 xf[4][2];
  float x2p[4];
#pragma unroll
  for (int rg = 0; rg < 4; ++rg) {
    x2p[rg] = 0.f;
    const int row = row0 + wave * 64 + rg * 16 + l15;
    const float* xp = x + (size_t)row * Fv + s * Dv + lg * 8;
#pragma unroll
    for (int h = 0; h < 2; ++h) {
      float4 f0 = *(const float4*)(xp + h * 32);
      float4 f1 = *(const float4*)(xp + h * 32 + 4);
      x2p[rg] += f0.x * f0.x + f0.y * f0.y + f0.z * f0.z + f0.w * f0.w
               + f1.x * f1.x + f1.y * f1.y + f1.z * f1.z + f1.w * f1.w;
      bf16x8 v;
      v[0] = (short)bf16rne(-f0.x); v[1] = (short)bf16rne(-f0.y);
      v[2] = (short)bf16rne(-f0.z); v[3] = (short)bf16rne(-f0.w);
      v[4] = (short)bf16rne(-f1.x); v[5] = (short)bf16rne(-f1.y);
      v[6] = (short)bf16rne(-f1.z); v[7] = (short)bf16rne(-f1.w);
      xf[rg][h] = v;
    }
  }

  float bestv[4];
  int besti[4];
#pragma unroll
  for (int rg = 0; rg < 4; ++rg) { bestv[rg] = 3.0e38f; besti[rg] = 0; }

  __syncthreads();  // c2 + chunk0 staged

  // ---- main loop: 8 chunks of 128 codewords (8 cw-tiles of 16)
  for (int c = 0; c < 8; ++c) {
    if (c < 7) {  // prefetch next chunk into other buffer
      const u16* srcb = swz_s + (size_t)(c + 1) * 128 * Dv;
#pragma unroll
      for (int it = 0; it < 4; ++it) {
        gload_lds16(srcb + (size_t)(it * BDIM + tid) * 8,
                    &cb_lds[(c + 1) & 1][(it * BDIM + (tid & ~63)) * 8]);
      }
    }
    const u16* cbb = cb_lds[c & 1];
    const int kc = c * 128 + lg * 4;
#pragma unroll
    for (int ct = 0; ct < 8; ++ct) {
      f32x4 c2v = *(const f32x4*)&c2_lds[c * 128 + ct * 16 + lg * 4];
      const u16* ap = &cbb[(ct * 16 + l15) * Dv];
      bf16x8 a0 = *(const bf16x8*)&ap[slotp0 * 8];
      bf16x8 a1 = *(const bf16x8*)&ap[slotp1 * 8];
#pragma unroll
      for (int rg = 0; rg < 4; ++rg) {
        f32x4 acc = c2v;
        acc = __builtin_amdgcn_mfma_f32_16x16x32_bf16(a0, xf[rg][0], acc, 0, 0, 0);
        acc = __builtin_amdgcn_mfma_f32_16x16x32_bf16(a1, xf[rg][1], acc, 0, 0, 0);
#pragma unroll
        for (int r = 0; r < 4; ++r) {
          float v = acc[r];
          int ki = kc + ct * 16 + r;
          bool p = v < bestv[rg];
          bestv[rg] = p ? v : bestv[rg];
          besti[rg] = p ? ki : besti[rg];
        }
      }
    }
    __syncthreads();  // drain prefetch; all waves done with current buffer
  }

  // ---- cross-lane argmin + x2 reduce (cols = l15 preserved; reduce over lg)
#pragma unroll
  for (int rg = 0; rg < 4; ++rg) {
    float bv = bestv[rg]; int bi = besti[rg]; float xx = x2p[rg];
#pragma unroll
    for (int st = 0; st < 2; ++st) {
      const int m = st == 0 ? 16 : 32;
      float ov = __shfl_xor(bv, m, 64);
      int oi = __shfl_xor(bi, m, 64);
      xx += __shfl_xor(xx, m, 64);
      bool p = (ov < bv) || (ov == bv && oi < bi);
      bv = p ? ov : bv; bi = p ? oi : bi;
    }
    bestv[rg] = bv; besti[rg] = bi; x2p[rg] = xx;
  }

  // ---- dev partial: dist_row = x2_row + 2*bestv_row; sum over the 16 cols
  float dev = 0.f;
#pragma unroll
  for (int rg = 0; rg < 4; ++rg) dev += x2p[rg] + 2.f * bestv[rg];
#pragma unroll
  for (int m = 1; m <= 8; m <<= 1) dev += __shfl_xor(dev, m, 64);
  if (lane == 0)
    devpart[((size_t)blockIdx.y * gridDim.x + blockIdx.x) * 4 + wave] = dev;

  // ---- quant write: copy selected codeword (exact fp32)
#pragma unroll
  for (int rg = 0; rg < 4; ++rg) {
    const int row = row0 + wave * 64 + rg * 16 + l15;
    const float* cp = cb + ((size_t)s * Kv + besti[rg]) * Dv + lg * 8;
    float* qp = quant + (size_t)row * Fv + s * Dv + lg * 8;
#pragma unroll
    for (int h = 0; h < 2; ++h) {
      float4 q0 = *(const float4*)(cp + h * 32);
      float4 q1 = *(const float4*)(cp + h * 32 + 4);
      *(float4*)(qp + h * 32) = q0;
      *(float4*)(qp + h * 32 + 4) = q1;
    }
  }
}

__global__ void dev_reduce(const float* __restrict__ part, float* __restrict__ out) {
  __shared__ float sred[256];
  int tid = threadIdx.x;
  float s = 0.f;
  for (int i = tid; i < 8192; i += 256) s += part[i];
  sred[tid] = s;
  __syncthreads();
  for (int off = 128; off > 0; off >>= 1) {
    if (tid < off) sred[tid] += sred[tid + off];
    __syncthreads();
  }
  if (tid == 0) out[0] = sred[0] * (1.25f / 4194304.0f);
}

extern "C" void kernel_launch(void* const* d_in, const int* in_sizes, int n_in,
                              void* d_out, int out_size, void* d_ws, size_t ws_size,
                              hipStream_t stream) {
  const float* x = (const float*)d_in[0];   // (B,N,F) fp32
  const float* cb = (const float*)d_in[1];  // (S,K,D) fp32
  float* quant = (float*)d_out;
  float* dev = quant + (size_t)Mv * Fv;

  // ws layout: swz bf16 codebook (1MB), c2h (32KB), dev partials (32KB)
  u16* swz = (u16*)d_ws;
  float* c2h = (float*)(swz + (size_t)Sv * Kv * Dv);
  float* part = c2h + Sv * Kv;

  prep_kernel<<<(Sv * Kv) / BDIM, BDIM, 0, stream>>>(cb, swz, c2h);
  dim3 grid(Mv / 256, Sv);
  pq_mfma<<<grid, BDIM, 0, stream>>>(x, cb, swz, c2h, quant, part);
  dev_reduce<<<1, 256, 0, stream>>>(part, dev);
}